// Round 13
// baseline (274.628 us; speedup 1.0000x reference)
//
#include <hip/hip_runtime.h>

#define L 256
#define BATCH 512
#define CIN 32
#define RNNIN 64
#define HIDN 128
#define OUTN 512

typedef _Float16 f16x8 __attribute__((ext_vector_type(8)));
typedef float f32x4 __attribute__((ext_vector_type(4)));

#define MFMA16(a, b, c) __builtin_amdgcn_mfma_f32_16x16x32_f16(a, b, c, 0, 0, 0)

// ws layout (bytes): hs @ 0 (33554432) fp16 hs[t*65536 + b*128 + j]

// MFMA RNN, fp16 2-term split (W to 22 bits; h/x fresh 11-bit noise per step).
// 32 blocks (16 batch rows) x 512 thr (8 waves, 2/SIMD). Wave w owns j-slice
// [16w,16w+16) = one 16x16 tile, full K=128.
// vs R10 (1085 cyc/step): 4 MFMA chains <=3 deep (x-chains issue immediately
// post-barrier from register operands, covering h ds_read latency), x B-frag
// register-prefetched 1 step ahead. NO register hs buffer (R12's scratch-spill
// lesson), per-step direct b64 store. Prep folded in: A-frags built in-lane
// from fp32 W_hh; Wc/bpre computed once per block (saves a ~28us launch slot).
__global__ __launch_bounds__(512, 1) void rnn_kernel(
    const float* __restrict__ x, const float* __restrict__ h0,
    const float* __restrict__ W_in, const float* __restrict__ b_in,
    const float* __restrict__ W_ih, const float* __restrict__ b_ih,
    const float* __restrict__ W_hh, const float* __restrict__ b_hh,
    unsigned short* __restrict__ hs)
{
    const int tid = threadIdx.x;
    const int bb = blockIdx.x;
    const int lane = tid & 63;
    const int w = tid >> 6;       // wave 0..7
    const int n = lane & 15;      // batch col / A row
    const int q = lane >> 4;      // quad

    __shared__ unsigned short hbuf[2][16][HIDN];     // 8 KB, granule swizzle ^(n&7)
    __shared__ unsigned short xc[2][16][16][CIN];    // 32 KB, [chunk][t&15][n][c]
    __shared__ float winlds[RNNIN * CIN];            // 8 KB
    __shared__ float binlds[RNNIN];
    __shared__ float bprelds[HIDN];

    const f32x4 ZERO4 = {0.f, 0.f, 0.f, 0.f};
    const int jr = w * 16 + n;    // A-row j for this lane

    // ---- in-kernel prep: stage W_in/b_in; bpre by first 128 threads ----
    for (int i = tid; i < RNNIN * CIN; i += 512) winlds[i] = W_in[i];
    if (tid < RNNIN) binlds[tid] = b_in[tid];
    __syncthreads();
    if (tid < HIDN) {
        const int j = tid;
        float bs = b_ih[j] + b_hh[j];
        for (int m = 0; m < RNNIN; ++m) bs += W_ih[j * RNNIN + m] * binlds[m];
        bprelds[j] = bs;
    }

    // ---- A-frags from fp32 W_hh, split fp16 hi/lo in registers ----
    f16x8 Ah[4], Al[4], Axh, Axl;
#pragma unroll
    for (int kc = 0; kc < 4; ++kc) {
        const float* src = W_hh + jr * HIDN + kc * 32 + q * 8;
        float4 va = *(const float4*)(src);
        float4 vb = *(const float4*)(src + 4);
        float vv[8] = {va.x, va.y, va.z, va.w, vb.x, vb.y, vb.z, vb.w};
#pragma unroll
        for (int i = 0; i < 8; ++i) {
            _Float16 h = (_Float16)vv[i];
            Ah[kc][i] = h;
            Al[kc][i] = (_Float16)(vv[i] - (float)h);
        }
    }
    // Wc row: wc[i] = dot64(W_ih[jr], W_in[:, q*8+i])
    {
        float wihr[RNNIN];
#pragma unroll
        for (int m = 0; m < RNNIN; m += 4) {
            float4 v = *(const float4*)(W_ih + jr * RNNIN + m);
            wihr[m] = v.x; wihr[m + 1] = v.y; wihr[m + 2] = v.z; wihr[m + 3] = v.w;
        }
#pragma unroll
        for (int i = 0; i < 8; ++i) {
            const int c = q * 8 + i;
            float acc = 0.f;
            for (int m = 0; m < RNNIN; ++m) acc += wihr[m] * winlds[m * CIN + c];
            _Float16 h = (_Float16)acc;
            Axh[i] = h;
            Axl[i] = (_Float16)(acc - (float)h);
        }
    }

    // ---- h0 -> fp16 plane, dbuf 0 (first 256 threads) ----
    if (tid < 256) {
        const int ni = tid >> 4, gi = tid & 15;
        const float4* src = (const float4*)(h0 + ((size_t)bb * 16 + ni) * HIDN + gi * 8);
        float4 a = src[0], b4 = src[1];
        float vv[8] = {a.x, a.y, a.z, a.w, b4.x, b4.y, b4.z, b4.w};
        unsigned short o[8];
#pragma unroll
        for (int i = 0; i < 8; ++i) {
            _Float16 h = (_Float16)vv[i];
            __builtin_memcpy(&o[i], &h, 2);
        }
        *(uint4*)&hbuf[0][ni][(gi ^ (ni & 7)) * 8] = *(uint4*)o;
    }

    // ---- x chunk staging over 512 threads: i=tid+r*512 -> (nn,cc,tq) ----
    float4 xr[4];
    auto issue_chunk = [&](int ci) {
#pragma unroll
        for (int r = 0; r < 4; ++r) {
            int i = tid + r * 512;
            int nn = i >> 7, cc = (i >> 2) & 31, tq = i & 3;
            xr[r] = *(const float4*)(x + (((size_t)bb * 16 + nn) * CIN + cc) * L + ci * 16 + tq * 4);
        }
    };
    auto write_chunk = [&](int buf) {
#pragma unroll
        for (int r = 0; r < 4; ++r) {
            int i = tid + r * 512;
            int nn = i >> 7, cc = (i >> 2) & 31, tq = i & 3;
            float vv[4] = {xr[r].x, xr[r].y, xr[r].z, xr[r].w};
#pragma unroll
            for (int k = 0; k < 4; ++k) {
                _Float16 h = (_Float16)vv[k];
                unsigned short u; __builtin_memcpy(&u, &h, 2);
                xc[buf][tq * 4 + k][nn][cc] = u;
            }
        }
    };

    issue_chunk(0);
    write_chunk(0);
    issue_chunk(1);
    __syncthreads();

    // bias for C/D rows j = w*16 + q*4 + r
    float4 bv = *(const float4*)(bprelds + w * 16 + q * 4);
    f32x4 bp = {bv.x, bv.y, bv.z, bv.w};

    unsigned short* hsp = hs + ((size_t)bb * 16 + n) * HIDN + w * 16 + q * 4;

    f16x8 xB, xBn;

#pragma unroll 2
    for (int t = 0; t < L; ++t) {
        const int p = t & 1;
        const int cb = (t >> 4) & 1, tt = t & 15;

        // post-barrier reads first
        f16x8 Bh[4];
#pragma unroll
        for (int kc = 0; kc < 4; ++kc)
            Bh[kc] = *(const f16x8*)&hbuf[p][n][((4 * kc + q) ^ (n & 7)) * 8];
        if (tt == 0) xB = *(const f16x8*)&xc[cb][0][n][q * 8];
        if (tt < 15) xBn = *(const f16x8*)&xc[cb][tt + 1][n][q * 8];  // prefetch

        // 4 chains <=3 deep; x-chains issue immediately (register operands)
        f32x4 c1 = MFMA16(Axh, xB, ZERO4);
        f32x4 c2 = MFMA16(Axl, xB, ZERO4);
        c1 = MFMA16(Ah[0], Bh[0], c1);
        c2 = MFMA16(Al[0], Bh[0], c2);
        f32x4 c0 = MFMA16(Ah[1], Bh[1], bp);
        f32x4 c3 = MFMA16(Al[1], Bh[1], ZERO4);
        c1 = MFMA16(Ah[2], Bh[2], c1);
        c2 = MFMA16(Al[2], Bh[2], c2);
        c0 = MFMA16(Ah[3], Bh[3], c0);
        c3 = MFMA16(Al[3], Bh[3], c3);
        f32x4 acc = (c0 + c1) + (c2 + c3);

        // tanh -> fp16 pack
        unsigned short o[4];
#pragma unroll
        for (int r = 0; r < 4; ++r) {
            float e = __expf(2.f * acc[r]);
            float hv = 1.f - 2.f * __builtin_amdgcn_rcpf(e + 1.f);
            _Float16 h = (_Float16)hv;
            __builtin_memcpy(&o[r], &h, 2);
        }
        uint2 pk; __builtin_memcpy(&pk, o, 8);
        const int G = (w * 2 + (q >> 1)) ^ (n & 7);
        *(uint2*)&hbuf[p ^ 1][n][G * 8 + (q & 1) * 4] = pk;   // critical publish
        *(uint2*)(hsp + (size_t)t * (BATCH * HIDN)) = pk;     // store, never waited

        if (tt == 15) {
            write_chunk(cb ^ 1);               // consumes 16-step-old loads
            const int nc = (t >> 4) + 2;
            if (nc < 16) issue_chunk(nc);
        }

        asm volatile("" ::: "memory");
        __builtin_amdgcn_s_waitcnt(0xC07F);    // lgkmcnt(0) only; stores in flight
        __builtin_amdgcn_s_barrier();
        asm volatile("" ::: "memory");
        xB = xBn;
    }
}

// Fused upsample(16->32, align_corners) + hardswish + mean + out-GEMM.
__global__ __launch_bounds__(256) void pool_out_kernel(
    const unsigned short* __restrict__ hs, const float* __restrict__ W_out,
    const float* __restrict__ b_out, float* __restrict__ out)
{
    const int b = blockIdx.x, tid = threadIdx.x;
    __shared__ unsigned short m[L][HIDN];   // 64 KB fp16
    __shared__ float ps[2][HIDN];
    __shared__ float pooled_s[HIDN];

#pragma unroll
    for (int it = 0; it < 16; ++it) {
        int i = tid + it * 256;
        int t = i >> 4, g = i & 15;
        *(uint4*)&m[t][g * 8] =
            *(const uint4*)(hs + (size_t)t * (BATCH * HIDN) + b * HIDN + g * 8);
    }
    __syncthreads();

    const int jo = tid & 127, sub = tid >> 7;
    float acc = 0.f;
    for (int oy = sub * 16; oy < sub * 16 + 16; ++oy) {
        float ysf = oy * (15.f / 31.f);
        int y0 = (int)ysf; float wy = ysf - (float)y0; int y1 = min(y0 + 1, 15);
        float rb[16];
#pragma unroll
        for (int sx = 0; sx < 16; ++sx) {
            float v0 = (float)*(const _Float16*)&m[y0 * 16 + sx][jo];
            float v1 = (float)*(const _Float16*)&m[y1 * 16 + sx][jo];
            rb[sx] = v0 + wy * (v1 - v0);
        }
#pragma unroll
        for (int ox = 0; ox < 32; ++ox) {
            float xsf = ox * (15.f / 31.f);
            int x0 = (int)xsf; float wx = xsf - (float)x0; int x1 = min(x0 + 1, 15);
            float v = rb[x0] + wx * (rb[x1] - rb[x0]);
            float t6 = fminf(fmaxf(v + 3.f, 0.f), 6.f);
            acc += v * t6;
        }
    }
    ps[sub][jo] = acc;
    __syncthreads();
    if (tid < 128) pooled_s[tid] = (ps[0][tid] + ps[1][tid]) * (1.f / 6144.f);
    __syncthreads();

    for (int o = tid; o < OUTN; o += 256) {
        float a = b_out[o];
#pragma unroll 8
        for (int k = 0; k < HIDN; k += 4) {
            float4 wv = *(const float4*)(W_out + o * HIDN + k);
            float4 pv = *(const float4*)&pooled_s[k];
            a += wv.x * pv.x + wv.y * pv.y + wv.z * pv.z + wv.w * pv.w;
        }
        out[b * OUTN + o] = a;
    }
}

extern "C" void kernel_launch(void* const* d_in, const int* in_sizes, int n_in,
                              void* d_out, int out_size, void* d_ws, size_t ws_size,
                              hipStream_t stream)
{
    const float* x     = (const float*)d_in[0];
    const float* h0    = (const float*)d_in[1];
    const float* W_in  = (const float*)d_in[2];
    const float* b_in  = (const float*)d_in[3];
    const float* W_ih  = (const float*)d_in[4];
    const float* b_ih  = (const float*)d_in[5];
    const float* W_hh  = (const float*)d_in[6];
    const float* b_hh  = (const float*)d_in[7];
    const float* W_out = (const float*)d_in[8];
    const float* b_out = (const float*)d_in[9];
    float* out = (float*)d_out;

    unsigned short* hsb = (unsigned short*)d_ws;

    rnn_kernel<<<32, 512, 0, stream>>>(x, h0, W_in, b_in, W_ih, b_ih, W_hh, b_hh, hsb);
    pool_out_kernel<<<512, 256, 0, stream>>>(hsb, W_out, b_out, out);
}